// Round 15
// baseline (100.735 us; speedup 1.0000x reference)
//
#include <hip/hip_runtime.h>

typedef float f32x4 __attribute__((ext_vector_type(4)));
typedef __bf16 bf16x8 __attribute__((ext_vector_type(8)));
typedef unsigned short u16x8 __attribute__((ext_vector_type(8)));

__device__ __forceinline__ unsigned short f2bf(float f) {
  union { float f; unsigned u; } v; v.f = f;
  unsigned r = v.u + 0x7FFFu + ((v.u >> 16) & 1u);
  return (unsigned short)(r >> 16);
}

__device__ __forceinline__ float min3f(float a, float b, float c) {
  return fminf(fminf(a, b), c);
}
__device__ __forceinline__ float max3f(float a, float b, float c) {
  return fmaxf(fmaxf(a, b), c);
}
__device__ __forceinline__ float med3f(float a, float b, float c) {
  return __builtin_amdgcn_fmed3f(a, b, c);
}

// async global->LDS, 16B per lane, LDS dest = wave-uniform base + lane*16
__device__ __forceinline__ void gload_lds16(const void* g, void* l) {
  __builtin_amdgcn_global_load_lds(
      (const __attribute__((address_space(1))) void*)g,
      (__attribute__((address_space(3))) void*)l, 16, 0, 0);
}

// conv_w fp32 [256][256] -> bf16 in MFMA-fragment-linear order:
// wbf[((ks*16 + ob)*64 + lane)*8 + j] = bf16(W[ob*16 + (lane&15)][ks*32 + (lane>>4)*8 + j])
__global__ void wconv_k(const float* __restrict__ w, unsigned short* __restrict__ wbf) {
  int idx  = blockIdx.x * 256 + threadIdx.x;   // 0..8191
  int lane = idx & 63;
  int ob   = (idx >> 6) & 15;
  int ks   = idx >> 10;                        // 0..7
  int o = (ob << 4) + (lane & 15);
  int c = (ks << 5) + ((lane >> 4) << 3);
  const float* src = w + (o << 8) + c;
  f32x4 v0 = *(const f32x4*)src;
  f32x4 v1 = *(const f32x4*)(src + 4);
  u16x8 ov;
  ov[0] = f2bf(v0[0]); ov[1] = f2bf(v0[1]); ov[2] = f2bf(v0[2]); ov[3] = f2bf(v0[3]);
  ov[4] = f2bf(v1[0]); ov[5] = f2bf(v1[1]); ov[6] = f2bf(v1[2]); ov[7] = f2bf(v1[3]);
  *(u16x8*)(wbf + (idx << 3)) = ov;
}

// One block = (batch, row-pair): 128 px x 256 oc, 512 THREADS (8 waves).
// Wave w owns oc-eighth [32w, 32w+32): acc = 64 regs/thread ->
// launch_bounds(512,4) targets 2 blocks/CU = 16 waves (2x R11's TLP).
// Port traffic unchanged vs R11 (stage 256 + wf 128 + write 131 MB).
// Median: 16 thr/channel, 4-px strips, 6-tap triplet network.
// Residual fold: wave w folds its oc slice at step ks == w (staged chans).
__launch_bounds__(512, 4)
__global__ void fused_k(const float* __restrict__ x,
                        const unsigned short* __restrict__ wbf,
                        const float* __restrict__ bias,
                        float* __restrict__ out) {
  __shared__ float Xs[128][64];            // 32 KB: row = ci*4+dr, granule-swizzled
  __shared__ unsigned short Bt[128][40];   // 10 KB: [px'][c-swizzled]

  const int t   = threadIdx.x;
  const int blk = blockIdx.x;
  const int swz = ((blk & 7) << 7) | (blk >> 3);   // XCD-bijective (1024 = 8*128)
  const int b   = swz >> 5;
  const int r0  = (swz & 31) << 1;         // rows r0, r0+1
  const int lane = t & 63;
  const int w    = t >> 6;       // wave 0..7
  const int g    = lane >> 4;    // lane group 0..3
  const int l15  = lane & 15;

  // median task: channel ci = t>>4 (0..31), strip s = lane&15 (4 px, both rows)
  const int ci  = t >> 4;
  const int s   = lane & 15;
  const int px0 = s << 2;
  const int cw  = ci ^ (((s >> 1) & 3) << 3);  // Bt swizzle (matches reader)
  const bool hasL = (s > 0), hasR = (s < 15);
  const bool zTop = (r0 == 0), zBot = (r0 == 62);

  const float* xb = x + ((size_t)b << 20);   // b * 256*64*64

  float bn[2];
  #pragma unroll
  for (int n = 0; n < 2; ++n) bn[n] = bias[(w << 5) + (n << 4) + l15];

  // staging: wave w stages channels cp = 4w+p (p 0..3), rows dr = lane>>4
  unsigned soff[4];
  #pragma unroll
  for (int p = 0; p < 4; ++p) {
    int cp = (w << 2) + p;
    int gr = r0 + (lane >> 4) - 1;
    gr = gr < 0 ? 0 : (gr > 63 ? 63 : gr);   // clamp; zeroed in VALU at median
    int gG = (lane & 15) ^ (cp & 3);         // pre-swizzle granule by cp&3
    soff[p] = ((unsigned)cp << 14) + ((unsigned)gr << 8) + ((unsigned)gG << 4);
  }

  auto stage = [&](int step) {
    const unsigned kso = (unsigned)step << 19;   // step * 32ch * 16KB
    #pragma unroll
    for (int p = 0; p < 4; ++p)
      gload_lds16((const char*)xb + (soff[p] + kso), &Xs[((w << 2) + p) << 2][0]);
  };

  f32x4 acc[8][2];
  #pragma unroll
  for (int m = 0; m < 8; ++m)
    #pragma unroll
    for (int n = 0; n < 2; ++n)
      acc[m][n] = (f32x4){0.f, 0.f, 0.f, 0.f};

  stage(0);
  __syncthreads();

  const int ri0 = ci << 2;
  const int gsw = s ^ (ci & 3);      // read granule (undo pre-swizzle)

  #pragma unroll
  for (int ks = 0; ks < 8; ++ks) {
    // --- W fragments (L2-hot, coalesced): ob = w*2+n ---
    bf16x8 wfc[2];
    #pragma unroll
    for (int n = 0; n < 2; ++n) {
      const int fidx = (((ks << 4) + (w << 1) + n) << 6) + lane;
      wfc[n] = __builtin_bit_cast(bf16x8, *(const u16x8*)(wbf + ((size_t)fidx << 3)));
    }

    // --- median source reads: 4 rows x 1 vec (4 px) ---
    f32x4 va[4];
    #pragma unroll
    for (int dr = 0; dr < 4; ++dr)
      va[dr] = *(const f32x4*)&Xs[ri0 + dr][gsw << 2];
    float le[4], re[4];
    #pragma unroll
    for (int dr = 0; dr < 4; ++dr) {
      le[dr] = __shfl_up(va[dr][3], 1);    // px0-1 from lane-1 (same channel)
      re[dr] = __shfl_down(va[dr][0], 1);  // px0+4 from lane+1
    }

    // --- residual fold: wave w's oc slice == channels staged at step w ---
    if (ks == w) {
      #pragma unroll
      for (int n = 0; n < 2; ++n) {
        const int cx = (n << 4) + l15;     // channel within staged group
        #pragma unroll
        for (int m = 0; m < 8; ++m) {
          const int dr = 1 + (m >> 2);
          const int gf = ((m & 3) << 2) + g;           // col granule of px'
          const int gs = gf ^ (cx & 3);
          const f32x4 xv = *(const f32x4*)&Xs[(cx << 2) + dr][gs << 2];
          acc[m][n] += xv;
        }
      }
    }

    // --- medians: 6 taps [le, va0..3, re] per row; strips A (r0) & B (r0+1) ---
    #pragma unroll
    for (int strip = 0; strip < 2; ++strip) {
      const int d0 = strip;              // rows d0, d0+1, d0+2
      float R0[6], R1[6], R2[6];
      R0[0] = hasL ? le[d0]     : 0.f;  R0[5] = hasR ? re[d0]     : 0.f;
      R1[0] = hasL ? le[d0 + 1] : 0.f;  R1[5] = hasR ? re[d0 + 1] : 0.f;
      R2[0] = hasL ? le[d0 + 2] : 0.f;  R2[5] = hasR ? re[d0 + 2] : 0.f;
      #pragma unroll
      for (int j = 0; j < 4; ++j) {
        R0[1 + j] = va[d0][j];
        R1[1 + j] = va[d0 + 1][j];
        R2[1 + j] = va[d0 + 2][j];
      }
      if (strip == 0 && zTop) {
        #pragma unroll
        for (int j = 0; j < 6; ++j) R0[j] = 0.f;
      }
      if (strip == 1 && zBot) {
        #pragma unroll
        for (int j = 0; j < 6; ++j) R2[j] = 0.f;
      }
      float mn[6], md[6], mx[6];
      #pragma unroll
      for (int j = 0; j < 6; ++j) {
        mn[j] = min3f(R0[j], R1[j], R2[j]);
        md[j] = med3f(R0[j], R1[j], R2[j]);
        mx[j] = max3f(R0[j], R1[j], R2[j]);
      }
      #pragma unroll
      for (int i = 0; i < 4; ++i) {
        float t0 = max3f(mn[i], mn[i+1], mn[i+2]);
        float t1 = med3f(md[i], md[i+1], md[i+2]);
        float t2 = min3f(mx[i], mx[i+1], mx[i+2]);
        Bt[(strip << 6) + px0 + i][cw] = f2bf(med3f(t0, t1, t2));
      }
    }

    __syncthreads();   // [1] Bt published; all Xs reads drained (lgkm)

    if (ks < 7) stage(ks + 1);   // overwrite Xs (safe), drains at next barrier

    // --- P fragments + MFMA: px' = m*16+l15, oc = w*32+n*16+l15 ---
    #pragma unroll
    for (int m = 0; m < 8; ++m) {
      const int px = (m << 4) + l15;
      const int gc = (g ^ ((px >> 3) & 3)) << 3;
      bf16x8 pa = __builtin_bit_cast(bf16x8, *(const u16x8*)&Bt[px][gc]);
      #pragma unroll
      for (int n = 0; n < 2; ++n)
        acc[m][n] = __builtin_amdgcn_mfma_f32_16x16x32_bf16(pa, wfc[n], acc[m][n], 0, 0, 0);
    }

    if (ks < 7) __syncthreads();   // [2] stage landed + Bt consumed
  }

  // --- epilogue (write-only): px' = (m&3)*16+g*4+q, row r0+(m>>2) ---
  #pragma unroll
  for (int m = 0; m < 8; ++m) {
    #pragma unroll
    for (int n = 0; n < 2; ++n) {
      const int o = (w << 5) + (n << 4) + l15;
      const size_t idx = ((((size_t)b << 8) + (size_t)o) << 12)
                       + ((size_t)(r0 + (m >> 2)) << 6)
                       + (size_t)(((m & 3) << 4) + (g << 2));
      f32x4 res;
      #pragma unroll
      for (int q = 0; q < 4; ++q) res[q] = acc[m][n][q] + bn[n];
      *(f32x4*)(out + idx) = res;
    }
  }
}

extern "C" void kernel_launch(void* const* d_in, const int* in_sizes, int n_in,
                              void* d_out, int out_size, void* d_ws, size_t ws_size,
                              hipStream_t stream) {
  const float* x  = (const float*)d_in[0];
  const float* cw = (const float*)d_in[1];
  const float* cb = (const float*)d_in[2];
  float* out = (float*)d_out;
  unsigned short* wbf = (unsigned short*)d_ws;   // 128 KB fragment-linear W

  hipLaunchKernelGGL(wconv_k, dim3(32), dim3(256), 0, stream, cw, wbf);
  hipLaunchKernelGGL(fused_k, dim3(1024), dim3(512), 0, stream, x, wbf, cb, out);
}

// Round 16
// 66.072 us; speedup vs baseline: 1.5246x; 1.5246x over previous
//
#include <hip/hip_runtime.h>

typedef float f32x4 __attribute__((ext_vector_type(4)));
typedef __bf16 bf16x8 __attribute__((ext_vector_type(8)));
typedef unsigned short u16x8 __attribute__((ext_vector_type(8)));

__device__ __forceinline__ unsigned short f2bf(float f) {
  union { float f; unsigned u; } v; v.f = f;
  unsigned r = v.u + 0x7FFFu + ((v.u >> 16) & 1u);
  return (unsigned short)(r >> 16);
}

__device__ __forceinline__ float min3f(float a, float b, float c) {
  return fminf(fminf(a, b), c);
}
__device__ __forceinline__ float max3f(float a, float b, float c) {
  return fmaxf(fmaxf(a, b), c);
}
__device__ __forceinline__ float med3f(float a, float b, float c) {
  return __builtin_amdgcn_fmed3f(a, b, c);
}

// async global->LDS, 16B per lane, LDS dest = wave-uniform base + lane*16
__device__ __forceinline__ void gload_lds16(const void* g, void* l) {
  __builtin_amdgcn_global_load_lds(
      (const __attribute__((address_space(1))) void*)g,
      (__attribute__((address_space(3))) void*)l, 16, 0, 0);
}

// conv_w fp32 [256][256] -> bf16 in MFMA-fragment-linear order:
// wbf[((ks*16 + ob)*64 + lane)*8 + j] = bf16(W[ob*16 + (lane&15)][ks*32 + (lane>>4)*8 + j])
__global__ void wconv_k(const float* __restrict__ w, unsigned short* __restrict__ wbf) {
  int idx  = blockIdx.x * 256 + threadIdx.x;   // 0..8191
  int lane = idx & 63;
  int ob   = (idx >> 6) & 15;
  int ks   = idx >> 10;                        // 0..7
  int o = (ob << 4) + (lane & 15);
  int c = (ks << 5) + ((lane >> 4) << 3);
  const float* src = w + (o << 8) + c;
  f32x4 v0 = *(const f32x4*)src;
  f32x4 v1 = *(const f32x4*)(src + 4);
  u16x8 ov;
  ov[0] = f2bf(v0[0]); ov[1] = f2bf(v0[1]); ov[2] = f2bf(v0[2]); ov[3] = f2bf(v0[3]);
  ov[4] = f2bf(v1[0]); ov[5] = f2bf(v1[1]); ov[6] = f2bf(v1[2]); ov[7] = f2bf(v1[3]);
  *(u16x8*)(wbf + (idx << 3)) = ov;
}

// One block = (batch, row-pair): 128 px x 256 oc, 256 threads. R11 tile +
// DOUBLE-BUFFERED Xs: stage(ks+1) is issued at the STEP TOP into Xs[nxt]
// while the median reads Xs[cur] -> the stage has the whole wf+median
// phase (~2-3K cy) before the draining barrier, vs ~400 cy in R11.
// Occupancy is register-capped at 2 blocks/CU, so the extra 32 KB LDS is
// free. Plain __syncthreads correctness (reads of the overwritten buffer
// completed at the previous barrier).
__launch_bounds__(256, 2)
__global__ void fused_k(const float* __restrict__ x,
                        const unsigned short* __restrict__ wbf,
                        const float* __restrict__ bias,
                        float* __restrict__ out) {
  __shared__ float Xs[2][128][64];         // 64 KB: row = ci*4 + dr, px-granule swizzled
  __shared__ unsigned short Bt[128][40];   // 10 KB: [px'][c-swizzled]

  const int t   = threadIdx.x;
  const int blk = blockIdx.x;
  const int swz = ((blk & 7) << 7) | (blk >> 3);   // XCD-bijective (1024 = 8*128)
  const int b   = swz >> 5;
  const int r0  = (swz & 31) << 1;         // even row, rows r0 and r0+1
  const int lane = t & 63;
  const int w    = t >> 6;       // wave 0..3
  const int g    = lane >> 4;    // lane group 0..3
  const int l15  = lane & 15;

  // median task: channel ci = t>>3 (0..31), strip s = t&7 (8 px, both rows)
  const int ci  = t >> 3;
  const int s   = t & 7;
  const int px0 = s << 3;
  const int cw  = ci ^ ((s & 3) << 3);     // Bt bank-deconflict swizzle
  const bool hasL = (s > 0), hasR = (s < 7);
  const bool zTop = (r0 == 0), zBot = (r0 == 62);

  const float* xb = x + ((size_t)b << 20);   // b * 256*64*64

  float bn[4];
  #pragma unroll
  for (int n = 0; n < 4; ++n) bn[n] = bias[(w << 6) + (n << 4) + l15];

  // staging: issue p stages channel cp=8w+p, rows dr=lane>>4 (4 rows = 1 KB)
  unsigned soff[8];
  #pragma unroll
  for (int p = 0; p < 8; ++p) {
    int cp = (w << 3) + p;
    int gr = r0 + (lane >> 4) - 1;
    gr = gr < 0 ? 0 : (gr > 63 ? 63 : gr);   // clamp; zeroed in VALU at median
    int bG = (lane & 15) ^ p;                // pre-swizzle px-block by cp&7==p
    soff[p] = ((unsigned)cp << 14) + ((unsigned)gr << 8) + ((unsigned)bG << 4);
  }

  auto stage = [&](int step, int buf) {
    const unsigned kso = (unsigned)step << 19;   // step * 32ch * 16KB
    #pragma unroll
    for (int p = 0; p < 8; ++p)
      gload_lds16((const char*)xb + (soff[p] + kso), &Xs[buf][(w << 5) + (p << 2)][0]);
  };

  f32x4 acc[8][4];
  #pragma unroll
  for (int m = 0; m < 8; ++m)
    #pragma unroll
    for (int n = 0; n < 4; ++n)
      acc[m][n] = (f32x4){0.f, 0.f, 0.f, 0.f};

  stage(0, 0);
  __syncthreads();   // Xs[0] ready

  const int ri0 = ci << 2;
  const int sig = ci & 7;
  const int bA  = ((s << 1)) ^ sig;
  const int bB  = ((s << 1) | 1) ^ sig;

  #pragma unroll
  for (int ks = 0; ks < 8; ++ks) {
    const int cur = ks & 1;

    // --- stage ks+1 FIRST: full wf+median phase of latency cover before
    //     the draining barrier. Writes Xs[cur^1], whose step-(ks-1) readers
    //     all completed at the previous barrier. ---
    if (ks < 7) stage(ks + 1, cur ^ 1);

    // --- W fragments (L2-hot, coalesced) ---
    bf16x8 wfc[4];
    #pragma unroll
    for (int n = 0; n < 4; ++n) {
      const int fidx = (((ks << 4) + (w << 2) + n) << 6) + lane;
      wfc[n] = __builtin_bit_cast(bf16x8, *(const u16x8*)(wbf + ((size_t)fidx << 3)));
    }

    // --- median source reads: 4 rows x 2 vecs from Xs[cur] ---
    f32x4 va[4], vb[4];
    #pragma unroll
    for (int dr = 0; dr < 4; ++dr) {
      const float* rp = &Xs[cur][ri0 + dr][0];
      va[dr] = *(const f32x4*)(rp + (bA << 2));
      vb[dr] = *(const f32x4*)(rp + (bB << 2));
    }
    float le[4], re[4];
    #pragma unroll
    for (int dr = 0; dr < 4; ++dr) {
      le[dr] = __shfl_up(vb[dr][3], 1);
      re[dr] = __shfl_down(va[dr][0], 1);
    }

    // --- residual fold: at step ks = 2w+h, staged channels ARE wave w's
    //     out-channels for n in {2h, 2h+1}; rows r0,r0+1 = dr 1,2 ---
    if ((ks >> 1) == w) {
      const int h = ks & 1;
      #pragma unroll
      for (int nn = 0; nn < 2; ++nn) {
        const int n  = (h << 1) + nn;
        const int cx = (nn << 4) + l15;
        const int sx = cx & 7;
        const int rb = cx << 2;
        #pragma unroll
        for (int m = 0; m < 8; ++m) {
          const int bL = ((((m & 3) << 2) + g) ^ sx) << 2;
          const f32x4 xv = *(const f32x4*)&Xs[cur][rb + 1 + (m >> 2)][bL];
          acc[m][n] += xv;
        }
      }
    }

    // --- strip A (output row r0): staged rows 0,1,2 ---
    {
      float R0[10], R1[10], R2[10];
      R0[0] = hasL ? le[0] : 0.f; R1[0] = hasL ? le[1] : 0.f; R2[0] = hasL ? le[2] : 0.f;
      R0[9] = hasR ? re[0] : 0.f; R1[9] = hasR ? re[1] : 0.f; R2[9] = hasR ? re[2] : 0.f;
      #pragma unroll
      for (int j = 0; j < 4; ++j) {
        R0[1 + j] = va[0][j]; R0[5 + j] = vb[0][j];
        R1[1 + j] = va[1][j]; R1[5 + j] = vb[1][j];
        R2[1 + j] = va[2][j]; R2[5 + j] = vb[2][j];
      }
      if (zTop) {
        #pragma unroll
        for (int j = 0; j < 10; ++j) R0[j] = 0.f;
      }
      float mn[10], md[10], mx[10];
      #pragma unroll
      for (int j = 0; j < 10; ++j) {
        mn[j] = min3f(R0[j], R1[j], R2[j]);
        md[j] = med3f(R0[j], R1[j], R2[j]);
        mx[j] = max3f(R0[j], R1[j], R2[j]);
      }
      #pragma unroll
      for (int i = 0; i < 8; ++i) {
        float t0 = max3f(mn[i], mn[i+1], mn[i+2]);
        float t1 = med3f(md[i], md[i+1], md[i+2]);
        float t2 = min3f(mx[i], mx[i+1], mx[i+2]);
        Bt[px0 + i][cw] = f2bf(med3f(t0, t1, t2));
      }
    }
    // --- strip B (output row r0+1): staged rows 1,2,3 ---
    {
      float R0[10], R1[10], R2[10];
      R0[0] = hasL ? le[1] : 0.f; R1[0] = hasL ? le[2] : 0.f; R2[0] = hasL ? le[3] : 0.f;
      R0[9] = hasR ? re[1] : 0.f; R1[9] = hasR ? re[2] : 0.f; R2[9] = hasR ? re[3] : 0.f;
      #pragma unroll
      for (int j = 0; j < 4; ++j) {
        R0[1 + j] = va[1][j]; R0[5 + j] = vb[1][j];
        R1[1 + j] = va[2][j]; R1[5 + j] = vb[2][j];
        R2[1 + j] = va[3][j]; R2[5 + j] = vb[3][j];
      }
      if (zBot) {
        #pragma unroll
        for (int j = 0; j < 10; ++j) R2[j] = 0.f;
      }
      float mn[10], md[10], mx[10];
      #pragma unroll
      for (int j = 0; j < 10; ++j) {
        mn[j] = min3f(R0[j], R1[j], R2[j]);
        md[j] = med3f(R0[j], R1[j], R2[j]);
        mx[j] = max3f(R0[j], R1[j], R2[j]);
      }
      #pragma unroll
      for (int i = 0; i < 8; ++i) {
        float t0 = max3f(mn[i], mn[i+1], mn[i+2]);
        float t1 = med3f(md[i], md[i+1], md[i+2]);
        float t2 = min3f(mx[i], mx[i+1], mx[i+2]);
        Bt[64 + px0 + i][cw] = f2bf(med3f(t0, t1, t2));
      }
    }

    __syncthreads();   // Bt published; stage(ks+1) landed (full-phase cover)

    // --- P fragments + MFMA: px' = m*16+l15 (m 0..7), oc = w*64+n*16+l15 ---
    bf16x8 pa[8];
    #pragma unroll
    for (int m = 0; m < 8; ++m) {
      const int px = (m << 4) + l15;
      const int gc = (g ^ ((px >> 3) & 3)) << 3;
      pa[m] = __builtin_bit_cast(bf16x8, *(const u16x8*)&Bt[px][gc]);
    }
    #pragma unroll
    for (int m = 0; m < 8; ++m)
      #pragma unroll
      for (int n = 0; n < 4; ++n)
        acc[m][n] = __builtin_amdgcn_mfma_f32_16x16x32_bf16(pa[m], wfc[n], acc[m][n], 0, 0, 0);

    if (ks < 7) __syncthreads();   // Bt consumed by all before next overwrite
  }

  // --- epilogue (write-only): px' = (m&3)*16+g*4+q, row r0+(m>>2) ---
  #pragma unroll
  for (int m = 0; m < 8; ++m) {
    #pragma unroll
    for (int n = 0; n < 4; ++n) {
      const int o = (w << 6) + (n << 4) + l15;
      const size_t idx = ((((size_t)b << 8) + (size_t)o) << 12)
                       + ((size_t)(r0 + (m >> 2)) << 6)
                       + (size_t)(((m & 3) << 4) + (g << 2));
      f32x4 res;
      #pragma unroll
      for (int q = 0; q < 4; ++q) res[q] = acc[m][n][q] + bn[n];
      *(f32x4*)(out + idx) = res;
    }
  }
}

extern "C" void kernel_launch(void* const* d_in, const int* in_sizes, int n_in,
                              void* d_out, int out_size, void* d_ws, size_t ws_size,
                              hipStream_t stream) {
  const float* x  = (const float*)d_in[0];
  const float* cw = (const float*)d_in[1];
  const float* cb = (const float*)d_in[2];
  float* out = (float*)d_out;
  unsigned short* wbf = (unsigned short*)d_ws;   // 128 KB fragment-linear W

  hipLaunchKernelGGL(wconv_k, dim3(32), dim3(256), 0, stream, cw, wbf);
  hipLaunchKernelGGL(fused_k, dim3(1024), dim3(256), 0, stream, x, wbf, cb, out);
}